// Round 1
// baseline (1700.686 us; speedup 1.0000x reference)
//
#include <hip/hip_runtime.h>

#define TSEQ   1024
#define DMODEL 1024
#define NB     4
#define NHEADS 16
#define HDIM   64

// Y[M,N] = A[M,K] @ W[N,K]^T   (A, W row-major; we dot rows of A with rows of W)
// Block: 64x64 output tile, 256 threads, 4x4 register micro-tile, BK=16.
__global__ __launch_bounds__(256) void gemm_bt_f32(
    const float* __restrict__ A, const float* __restrict__ W,
    float* __restrict__ Y, int M, int N, int K)
{
    __shared__ float As[64][17];   // +1 pad: conflict-free column reads
    __shared__ float Ws[64][17];
    const int t    = threadIdx.x;
    const int row0 = blockIdx.x * 64;
    const int col0 = blockIdx.y * 64;
    const int tr   = (t >> 4) << 2;   // this thread's 4 output rows (local)
    const int tc   = (t & 15) << 2;   // this thread's 4 output cols (local)
    const int lr   = t >> 2;          // staging: row 0..63
    const int lc   = (t & 3) << 2;    // staging: 4 floats at col lc

    float acc[4][4] = {};

    for (int k0 = 0; k0 < K; k0 += 16) {
        float4 a4 = *(const float4*)(A + (size_t)(row0 + lr) * K + k0 + lc);
        float4 w4 = *(const float4*)(W + (size_t)(col0 + lr) * K + k0 + lc);
        As[lr][lc + 0] = a4.x; As[lr][lc + 1] = a4.y;
        As[lr][lc + 2] = a4.z; As[lr][lc + 3] = a4.w;
        Ws[lr][lc + 0] = w4.x; Ws[lr][lc + 1] = w4.y;
        Ws[lr][lc + 2] = w4.z; Ws[lr][lc + 3] = w4.w;
        __syncthreads();
#pragma unroll
        for (int kk = 0; kk < 16; ++kk) {
            const float a0 = As[tr + 0][kk], a1 = As[tr + 1][kk];
            const float a2 = As[tr + 2][kk], a3 = As[tr + 3][kk];
            const float b0 = Ws[tc + 0][kk], b1 = Ws[tc + 1][kk];
            const float b2 = Ws[tc + 2][kk], b3 = Ws[tc + 3][kk];
            acc[0][0] += a0 * b0; acc[0][1] += a0 * b1; acc[0][2] += a0 * b2; acc[0][3] += a0 * b3;
            acc[1][0] += a1 * b0; acc[1][1] += a1 * b1; acc[1][2] += a1 * b2; acc[1][3] += a1 * b3;
            acc[2][0] += a2 * b0; acc[2][1] += a2 * b1; acc[2][2] += a2 * b2; acc[2][3] += a2 * b3;
            acc[3][0] += a3 * b0; acc[3][1] += a3 * b1; acc[3][2] += a3 * b2; acc[3][3] += a3 * b3;
        }
        __syncthreads();
    }
#pragma unroll
    for (int i = 0; i < 4; ++i) {
        float4 o4 = make_float4(acc[i][0], acc[i][1], acc[i][2], acc[i][3]);
        *(float4*)(Y + (size_t)(row0 + tr + i) * N + col0 + tc) = o4;
    }
}

// Based attention, one block per (query-tile qt, head h, batch b).
// q/k/v stored as (B*T, D) row-major; head h occupies columns [h*64, h*64+64).
// score = 1 + s + 0.5 s^2, s = (q.k)/sqrt(64); causal; o = (S @ v) / rowsum(S).
__global__ __launch_bounds__(256) void based_attn_f32(
    const float* __restrict__ Q, const float* __restrict__ Km,
    const float* __restrict__ V, float* __restrict__ O)
{
    __shared__ float qs[64][HDIM + 1];
    __shared__ float ks[64][HDIM + 1];
    __shared__ float vs[64][HDIM + 1];
    __shared__ float Ss[64][65];

    const int t  = threadIdx.x;
    const int qt = blockIdx.x;   // 0..15
    const int h  = blockIdx.y;   // 0..15
    const int b  = blockIdx.z;   // 0..3

    const int lr   = t >> 2;          // 0..63 : row handled for staging + output
    const int lc   = (t & 3) << 4;    // 0,16,32,48 : 16-dim slice
    const int r    = lr;              // this thread's query row (local)
    const int dim0 = lc;              // this thread's 16 output dims

    const size_t rowbase = ((size_t)b * TSEQ) * DMODEL + (size_t)h * HDIM;

    // load q tile (64 rows x 64 dims)
    {
        const float* src = Q + rowbase + (size_t)(qt * 64 + lr) * DMODEL + lc;
#pragma unroll
        for (int i = 0; i < 16; i += 4) {
            float4 v4 = *(const float4*)(src + i);
            qs[lr][lc + i + 0] = v4.x; qs[lr][lc + i + 1] = v4.y;
            qs[lr][lc + i + 2] = v4.z; qs[lr][lc + i + 3] = v4.w;
        }
    }

    float num[16] = {};
    float den = 0.f;

    for (int kt = 0; kt <= qt; ++kt) {
        const float* ksrc = Km + rowbase + (size_t)(kt * 64 + lr) * DMODEL + lc;
        const float* vsrc = V  + rowbase + (size_t)(kt * 64 + lr) * DMODEL + lc;
#pragma unroll
        for (int i = 0; i < 16; i += 4) {
            float4 k4 = *(const float4*)(ksrc + i);
            ks[lr][lc + i + 0] = k4.x; ks[lr][lc + i + 1] = k4.y;
            ks[lr][lc + i + 2] = k4.z; ks[lr][lc + i + 3] = k4.w;
            float4 v4 = *(const float4*)(vsrc + i);
            vs[lr][lc + i + 0] = v4.x; vs[lr][lc + i + 1] = v4.y;
            vs[lr][lc + i + 2] = v4.z; vs[lr][lc + i + 3] = v4.w;
        }
        __syncthreads();   // covers qs (first iter) + ks/vs

        // Phase A: 64x64 score tile -> Ss
#pragma unroll 1
        for (int idx = t; idx < 64 * 64; idx += 256) {
            const int sr = idx >> 6;
            const int sc = idx & 63;
            float dot = 0.f;
#pragma unroll
            for (int kk = 0; kk < 64; ++kk)
                dot += qs[sr][kk] * ks[sc][kk];
            const float sv = dot * 0.125f;           // 1/sqrt(64)
            float scv = 1.0f + sv + 0.5f * sv * sv;  // always > 0
            if (kt * 64 + sc > qt * 64 + sr) scv = 0.f;
            Ss[sr][sc] = scv;
        }
        __syncthreads();

        // Phase B: num += S @ v ; den += rowsum(S)
#pragma unroll 1
        for (int s = 0; s < 64; ++s) {
            const float w = Ss[r][s];
            den += w;
#pragma unroll
            for (int i = 0; i < 16; ++i)
                num[i] += w * vs[s][dim0 + i];
        }
        __syncthreads();   // before next iter overwrites ks/vs/Ss
    }

    const float inv = 1.0f / den;
    float* dst = O + rowbase + (size_t)(qt * 64 + r) * DMODEL + dim0;
#pragma unroll
    for (int i = 0; i < 16; i += 4) {
        float4 o4 = make_float4(num[i] * inv, num[i + 1] * inv,
                                num[i + 2] * inv, num[i + 3] * inv);
        *(float4*)(dst + i) = o4;
    }
}

extern "C" void kernel_launch(void* const* d_in, const int* in_sizes, int n_in,
                              void* d_out, int out_size, void* d_ws, size_t ws_size,
                              hipStream_t stream) {
    const float* x  = (const float*)d_in[0];
    const float* Wq = (const float*)d_in[1];
    const float* Wk = (const float*)d_in[2];
    const float* Wv = (const float*)d_in[3];
    const float* Wo = (const float*)d_in[4];
    float* out = (float*)d_out;

    const int M = NB * TSEQ;   // 4096
    const int N = DMODEL;      // 1024
    const int K = DMODEL;      // 1024

    float* q = (float*)d_ws;
    float* k = q + (size_t)M * N;
    float* v = k + (size_t)M * N;
    float* o = v + (size_t)M * N;   // total 64 MiB scratch

    dim3 gg(M / 64, N / 64);   // 64 x 16 blocks
    gemm_bt_f32<<<gg, 256, 0, stream>>>(x, Wq, q, M, N, K);
    gemm_bt_f32<<<gg, 256, 0, stream>>>(x, Wk, k, M, N, K);
    gemm_bt_f32<<<gg, 256, 0, stream>>>(x, Wv, v, M, N, K);

    dim3 ga(TSEQ / 64, NHEADS, NB);  // 16 x 16 x 4 blocks
    based_attn_f32<<<ga, 256, 0, stream>>>(q, k, v, o);

    gemm_bt_f32<<<gg, 256, 0, stream>>>(o, Wo, out, M, N, K);
}

// Round 2
// 196.731 us; speedup vs baseline: 8.6447x; 8.6447x over previous
//
#include <hip/hip_runtime.h>

typedef unsigned short u16;
typedef __attribute__((ext_vector_type(8))) short bf16x8;   // MFMA A/B frag (8 bf16)
typedef __attribute__((ext_vector_type(8))) unsigned short u16x8;
typedef __attribute__((ext_vector_type(4))) unsigned short u16x4;
typedef __attribute__((ext_vector_type(4))) float f32x4;    // MFMA C/D frag

#define MFMA16(a, b, c) __builtin_amdgcn_mfma_f32_16x16x32_bf16((a), (b), (c), 0, 0, 0)

// async global->LDS, 16B per lane; LDS dest = wave-uniform base + lane*16
__device__ __forceinline__ void gll16(const void* g, void* l) {
    __builtin_amdgcn_global_load_lds(
        (const __attribute__((address_space(1))) unsigned int*)g,
        (__attribute__((address_space(3))) unsigned int*)l, 16, 0, 0);
}

__device__ __forceinline__ u16 f2b(float f) {   // f32 -> bf16 RNE
    unsigned int u = __float_as_uint(f);
    u += 0x7fffu + ((u >> 16) & 1u);
    return (u16)(u >> 16);
}

// ---------------------------------------------------------------- cast f32->bf16
__global__ __launch_bounds__(256) void cast_bf16(const float* __restrict__ s,
                                                 u16* __restrict__ d, int n) {
    int i = (blockIdx.x * 256 + threadIdx.x) * 8;
    if (i >= n) return;
    float4 a = *(const float4*)(s + i);
    float4 b = *(const float4*)(s + i + 4);
    u16x8 r;
    r[0] = f2b(a.x); r[1] = f2b(a.y); r[2] = f2b(a.z); r[3] = f2b(a.w);
    r[4] = f2b(b.x); r[5] = f2b(b.y); r[6] = f2b(b.z); r[7] = f2b(b.w);
    *(u16x8*)(d + i) = r;
}

// ---------------------------------------------------------------- GEMM (m97 style)
// Y[M,N] = A[M,K] @ W[N,K]^T, bf16 in, fp32 acc. 128x128 tile, BK=32, 4 waves.
template <int OUT_BF16>
__global__ __launch_bounds__(256) void gemm_bt(const u16* __restrict__ A,
                                               const u16* __restrict__ W,
                                               void* __restrict__ Yv,
                                               int M, int N, int K) {
    __shared__ u16 As[128 * 32];   // [row][32] rows of the 128x32 A-tile
    __shared__ u16 Bs[128 * 32];
    const int t = threadIdx.x, w = t >> 6, lane = t & 63;
    const int quad = lane >> 4, m16 = lane & 15;
    const int wr = (w >> 1) * 64, wc = (w & 1) * 64;
    const int row0 = blockIdx.x * 128, col0 = blockIdx.y * 128;
    const int srow = lane >> 2;           // staging: row within 16-row chunk
    const int scol = (lane & 3) * 8;      // staging: 8-elem col offset

    f32x4 acc[4][4];
#pragma unroll
    for (int i = 0; i < 4; ++i)
#pragma unroll
        for (int j = 0; j < 4; ++j) acc[i][j] = (f32x4){0.f, 0.f, 0.f, 0.f};

    for (int k0 = 0; k0 < K; k0 += 32) {
#pragma unroll
        for (int cc = 0; cc < 2; ++cc) {
            const int c = w * 2 + cc;           // chunk 0..7 (16 rows x 64B)
            const int rr = c * 16 + srow;
            gll16(A + (size_t)(row0 + rr) * K + k0 + scol, &As[c * 512]);
            gll16(W + (size_t)(col0 + rr) * K + k0 + scol, &Bs[c * 512]);
        }
        __syncthreads();
        bf16x8 af[4], bf[4];
#pragma unroll
        for (int i = 0; i < 4; ++i)
            af[i] = *(const bf16x8*)&As[(wr + i * 16 + m16) * 32 + quad * 8];
#pragma unroll
        for (int j = 0; j < 4; ++j)
            bf[j] = *(const bf16x8*)&Bs[(wc + j * 16 + m16) * 32 + quad * 8];
#pragma unroll
        for (int i = 0; i < 4; ++i)
#pragma unroll
            for (int j = 0; j < 4; ++j) acc[i][j] = MFMA16(af[i], bf[j], acc[i][j]);
        __syncthreads();
    }
    // epilogue: D[row=quad*4+r][col=m16] per 16x16 tile
#pragma unroll
    for (int i = 0; i < 4; ++i)
#pragma unroll
        for (int j = 0; j < 4; ++j)
#pragma unroll
            for (int r = 0; r < 4; ++r) {
                const int rg = row0 + wr + i * 16 + quad * 4 + r;
                const int cg = col0 + wc + j * 16 + m16;
                if (OUT_BF16)
                    ((u16*)Yv)[(size_t)rg * N + cg] = f2b(acc[i][j][r]);
                else
                    ((float*)Yv)[(size_t)rg * N + cg] = acc[i][j][r];
            }
}

// ---------------------------------------------------------------- v -> vT
// v rows: token (stride vstride, col h*64+vd) -> vT rows: (b*16+h)*64+vd, 1024 tokens
__global__ __launch_bounds__(256) void transpose_v(const u16* __restrict__ v,
                                                   u16* __restrict__ vT, int vstride) {
    __shared__ u16 tile[64][72];
    const int t = threadIdx.x;
    const int tt = blockIdx.x, h = blockIdx.y, b = blockIdx.z;
    {
        const int row = t >> 2, c4 = (t & 3) * 16;
        const u16* src = v + (size_t)(b * 1024 + tt * 64 + row) * vstride + h * 64 + c4;
        *(u16x8*)&tile[row][c4] = *(const u16x8*)src;
        *(u16x8*)&tile[row][c4 + 8] = *(const u16x8*)(src + 8);
    }
    __syncthreads();
    const int vd = t >> 2, tk = (t & 3) * 16;
    u16 tmp[16];
#pragma unroll
    for (int j = 0; j < 16; ++j) tmp[j] = tile[tk + j][vd];
    u16* dst = vT + (size_t)((b * 16 + h) * 64 + vd) * 1024 + tt * 64 + tk;
    *(u16x8*)dst = *(u16x8*)tmp;
    *(u16x8*)(dst + 8) = *(u16x8*)(tmp + 8);
}

// ---------------------------------------------------------------- based attention
// Block: 128 q-rows for one (b,h). S^T = K*Q^T (packed Ss writes), num = Ss*V,
// den via ones-B-frag MFMA. q/k row stride 3072 (fused qkv), vT stride 1024.
__global__ __launch_bounds__(256) void based_attn(const u16* __restrict__ q,
                                                  const u16* __restrict__ k,
                                                  const u16* __restrict__ vT,
                                                  u16* __restrict__ o) {
    __shared__ u16 qs[2][128][32];   // [d-block][q][32]
    __shared__ u16 ks[2][64][32];    // [d-block][key][32]
    __shared__ u16 vs[2][64][32];    // [key-block][vdim][32 keys]
    __shared__ u16 Ss[2][128][32];   // [key-block][q][32 keys]

    const int t = threadIdx.x, w = t >> 6, lane = t & 63;
    const int quad = lane >> 4, m16 = lane & 15;
    const int qt2 = blockIdx.x, h = blockIdx.y, b = blockIdx.z;
    const int Q0 = qt2 * 128;
    const int srow = lane >> 2, s8 = (lane & 3) * 8;

    // stage q tile (16 chunks of 1KB; wave w: 4w..4w+3)
#pragma unroll
    for (int cc = 0; cc < 4; ++cc) {
        const int c = w * 4 + cc;
        const int dblk = c >> 3, rr = (c & 7) * 16 + srow;
        gll16(q + (size_t)(b * 1024 + Q0 + rr) * 3072 + h * 64 + dblk * 32 + s8,
              &qs[dblk][(c & 7) * 16][0]);
    }

    bf16x8 ones;
#pragma unroll
    for (int e = 0; e < 8; ++e) ones[e] = (short)0x3F80;

    f32x4 num[2][4], den[2];
#pragma unroll
    for (int i = 0; i < 2; ++i) {
        den[i] = (f32x4){0.f, 0.f, 0.f, 0.f};
#pragma unroll
        for (int j = 0; j < 4; ++j) num[i][j] = (f32x4){0.f, 0.f, 0.f, 0.f};
    }

    const int ktmax = 2 * qt2 + 1;
    for (int kt = 0; kt <= ktmax; ++kt) {
        // stage k (8 chunks) and vT (8 chunks); wave w: chunks 2w, 2w+1
#pragma unroll
        for (int cc = 0; cc < 2; ++cc) {
            const int c = w * 2 + cc;
            const int blk = c >> 2, rr = (c & 3) * 16 + srow;
            gll16(k + (size_t)(b * 1024 + kt * 64 + rr) * 3072 + h * 64 + blk * 32 + s8,
                  &ks[blk][(c & 3) * 16][0]);
            gll16(vT + (size_t)((b * 16 + h) * 64 + rr) * 1024 + kt * 64 + blk * 32 + s8,
                  &vs[blk][(c & 3) * 16][0]);
        }
        __syncthreads();

        // Phase 1: S^T tiles: D[key][q] = K[key][d] * Q^T[d][q]
        f32x4 sacc[2][4];
#pragma unroll
        for (int iq = 0; iq < 2; ++iq)
#pragma unroll
            for (int jk = 0; jk < 4; ++jk) sacc[iq][jk] = (f32x4){0.f, 0.f, 0.f, 0.f};
#pragma unroll
        for (int kd = 0; kd < 2; ++kd) {
            bf16x8 af[4], qf[2];
#pragma unroll
            for (int jk = 0; jk < 4; ++jk)
                af[jk] = *(const bf16x8*)&ks[kd][jk * 16 + m16][quad * 8];
#pragma unroll
            for (int iq = 0; iq < 2; ++iq)
                qf[iq] = *(const bf16x8*)&qs[kd][w * 32 + iq * 16 + m16][quad * 8];
#pragma unroll
            for (int iq = 0; iq < 2; ++iq)
#pragma unroll
                for (int jk = 0; jk < 4; ++jk)
                    sacc[iq][jk] = MFMA16(af[jk], qf[iq], sacc[iq][jk]);
        }
        // transform + packed write: lane's 4 regs = 4 consecutive keys of query m16
#pragma unroll
        for (int iq = 0; iq < 2; ++iq) {
            const int qglob = Q0 + w * 32 + iq * 16 + m16;
#pragma unroll
            for (int jk = 0; jk < 4; ++jk) {
                const int key0 = kt * 64 + jk * 16 + quad * 4;
                u16x4 pk;
#pragma unroll
                for (int r = 0; r < 4; ++r) {
                    const float s = sacc[iq][jk][r] * 0.125f;   // 1/sqrt(64)
                    float sc = 1.0f + s + 0.5f * s * s;
                    if (key0 + r > qglob) sc = 0.f;
                    pk[r] = f2b(sc);
                }
                const int kl = jk * 16 + quad * 4;
                *(u16x4*)&Ss[kl >> 5][w * 32 + iq * 16 + m16][kl & 31] = pk;
            }
        }
        __syncthreads();

        // Phase 2: num += Ss * V (B from vT layout), den += Ss * ones
#pragma unroll
        for (int kb = 0; kb < 2; ++kb) {
            bf16x8 sf[2], vf[4];
#pragma unroll
            for (int i = 0; i < 2; ++i)
                sf[i] = *(const bf16x8*)&Ss[kb][w * 32 + i * 16 + m16][quad * 8];
#pragma unroll
            for (int j = 0; j < 4; ++j)
                vf[j] = *(const bf16x8*)&vs[kb][j * 16 + m16][quad * 8];
#pragma unroll
            for (int i = 0; i < 2; ++i) {
#pragma unroll
                for (int j = 0; j < 4; ++j) num[i][j] = MFMA16(sf[i], vf[j], num[i][j]);
                den[i] = MFMA16(sf[i], ones, den[i]);
            }
        }
        __syncthreads();
    }

    // epilogue: o[q][h*64+vdim] = num/den, bf16
#pragma unroll
    for (int i = 0; i < 2; ++i)
#pragma unroll
        for (int r = 0; r < 4; ++r) {
            const float inv = 1.0f / den[i][r];
            const int tok = b * 1024 + Q0 + w * 32 + i * 16 + quad * 4 + r;
#pragma unroll
            for (int j = 0; j < 4; ++j)
                o[(size_t)tok * 1024 + h * 64 + j * 16 + m16] = f2b(num[i][j][r] * inv);
        }
}

// ---------------------------------------------------------------- launch
extern "C" void kernel_launch(void* const* d_in, const int* in_sizes, int n_in,
                              void* d_out, int out_size, void* d_ws, size_t ws_size,
                              hipStream_t stream) {
    const float* x  = (const float*)d_in[0];
    const float* Wq = (const float*)d_in[1];
    const float* Wk = (const float*)d_in[2];
    const float* Wv = (const float*)d_in[3];
    const float* Wo = (const float*)d_in[4];
    float* out = (float*)d_out;

    const size_t MEL = 4096ull * 1024ull;   // 4M
    u16* xb   = (u16*)d_ws;          // 4M elems
    u16* Wqkv = xb + MEL;            // 3M (Wq|Wk|Wv rows concatenated)
    u16* Wob  = Wqkv + 3ull * 1024 * 1024;
    u16* qkv  = Wob + 1024ull * 1024;  // 4096 x 3072
    u16* vT   = qkv + 3ull * MEL;      // 1024-head-rows x 1024 tokens... (4M)
    u16* o    = vT + MEL;              // 4096 x 1024

    cast_bf16<<<2048, 256, 0, stream>>>(x, xb, 4194304);
    cast_bf16<<<512, 256, 0, stream>>>(Wq, Wqkv, 1048576);
    cast_bf16<<<512, 256, 0, stream>>>(Wk, Wqkv + 1048576, 1048576);
    cast_bf16<<<512, 256, 0, stream>>>(Wv, Wqkv + 2097152, 1048576);
    cast_bf16<<<512, 256, 0, stream>>>(Wo, Wob, 1048576);

    dim3 gq(32, 24);   // 4096/128 x 3072/128
    gemm_bt<1><<<gq, 256, 0, stream>>>(xb, Wqkv, qkv, 4096, 3072, 1024);

    dim3 gt(16, 16, 4);
    transpose_v<<<gt, 256, 0, stream>>>(qkv + 2048, vT, 3072);

    dim3 ga(8, 16, 4);   // 128-row q-tiles x heads x batch
    based_attn<<<ga, 256, 0, stream>>>(qkv, qkv + 1024, vT, o);

    dim3 go(32, 8);
    gemm_bt<0><<<go, 256, 0, stream>>>(o, Wob, (void*)out, 4096, 1024, 1024);
}

// Round 5
// 187.263 us; speedup vs baseline: 9.0818x; 1.0506x over previous
//
#include <hip/hip_runtime.h>

typedef unsigned short u16;
typedef __attribute__((ext_vector_type(8))) short bf16x8;   // MFMA A/B frag (8 bf16)
typedef __attribute__((ext_vector_type(8))) unsigned short u16x8;
typedef __attribute__((ext_vector_type(4))) float f32x4;    // MFMA C/D frag

#define MFMA16(a, b, c) __builtin_amdgcn_mfma_f32_16x16x32_bf16((a), (b), (c), 0, 0, 0)

// async global->LDS, 16B per lane; LDS dest = wave-uniform base + lane*16
__device__ __forceinline__ void gll16(const void* g, void* l) {
    __builtin_amdgcn_global_load_lds(
        (const __attribute__((address_space(1))) unsigned int*)g,
        (__attribute__((address_space(3))) unsigned int*)l, 16, 0, 0);
}

__device__ __forceinline__ u16 f2b(float f) {   // f32 -> bf16 RNE (scalar)
    unsigned int u = __float_as_uint(f);
    u += 0x7fffu + ((u >> 16) & 1u);
    return (u16)(u >> 16);
}

__device__ __forceinline__ unsigned int pkbf(float a, float b) {  // packed bf16x2
    return (unsigned int)f2b(a) | ((unsigned int)f2b(b) << 16);
}

// ---------------------------------------------------------------- casts
__global__ __launch_bounds__(256) void cast_x(const float* __restrict__ s,
                                              u16* __restrict__ d) {
    int i = (blockIdx.x * 256 + threadIdx.x) * 8;
    float4 a = *(const float4*)(s + i);
    float4 b = *(const float4*)(s + i + 4);
    uint4 r = make_uint4(pkbf(a.x, a.y), pkbf(a.z, a.w),
                         pkbf(b.x, b.y), pkbf(b.z, b.w));
    *(uint4*)(d + i) = r;
}

// all four 1024x1024 weights in one launch; dst = base + y*1M (Wq|Wk|Wv|Wo)
__global__ __launch_bounds__(256) void cast_w(const float* __restrict__ w0,
                                              const float* __restrict__ w1,
                                              const float* __restrict__ w2,
                                              const float* __restrict__ w3,
                                              u16* __restrict__ base) {
    const float* s = (blockIdx.y == 0) ? w0 : (blockIdx.y == 1) ? w1
                    : (blockIdx.y == 2) ? w2 : w3;
    u16* d = base + (size_t)blockIdx.y * 1048576;
    int i = (blockIdx.x * 256 + threadIdx.x) * 8;
    float4 a = *(const float4*)(s + i);
    float4 b = *(const float4*)(s + i + 4);
    uint4 r = make_uint4(pkbf(a.x, a.y), pkbf(a.z, a.w),
                         pkbf(b.x, b.y), pkbf(b.z, b.w));
    *(uint4*)(d + i) = r;
}

// ---------------------------------------------------------------- GEMM (m97 style)
// Y[M,N] = A[M,K] @ W[N,K]^T, bf16 in, fp32 acc. 128xBN tile, BK=32, 4 waves.
// BN=128: 2x2 wave grid, 4x4 frags. BN=64: 4x1 wave grid, 2x4 frags (2 blk/CU
// occupancy for launch-starved shapes).
template <int BN, int OUT_BF16>
__global__ __launch_bounds__(256) void gemm_bt(const u16* __restrict__ A,
                                               const u16* __restrict__ W,
                                               void* __restrict__ Yv,
                                               int M, int N, int K) {
    __shared__ u16 As[128 * 32];
    __shared__ u16 Bs[BN * 32];
    constexpr int MI = (BN == 128) ? 4 : 2;
    const int t = threadIdx.x, w = t >> 6, lane = t & 63;
    const int quad = lane >> 4, m16 = lane & 15;
    const int wr = (BN == 128) ? ((w >> 1) * 64) : (w * 32);
    const int wc = (BN == 128) ? ((w & 1) * 64) : 0;
    const int row0 = blockIdx.x * 128, col0 = blockIdx.y * BN;
    const int srow = lane >> 2;           // staging: row within 16-row chunk
    const int scol = (lane & 3) * 8;      // staging: 8-elem col offset

    f32x4 acc[MI][4];
#pragma unroll
    for (int i = 0; i < MI; ++i)
#pragma unroll
        for (int j = 0; j < 4; ++j) acc[i][j] = (f32x4){0.f, 0.f, 0.f, 0.f};

    for (int k0 = 0; k0 < K; k0 += 32) {
        if constexpr (BN == 128) {
#pragma unroll
            for (int cc = 0; cc < 2; ++cc) {
                const int c = w * 2 + cc;           // chunk 0..7 (16 rows x 64B)
                const int rr = c * 16 + srow;
                gll16(A + (size_t)(row0 + rr) * K + k0 + scol, &As[c * 512]);
                gll16(W + (size_t)(col0 + rr) * K + k0 + scol, &Bs[c * 512]);
            }
        } else {
#pragma unroll
            for (int cc = 0; cc < 2; ++cc) {
                const int c = w * 2 + cc;
                const int rr = c * 16 + srow;
                gll16(A + (size_t)(row0 + rr) * K + k0 + scol, &As[c * 512]);
            }
            {
                const int rr = w * 16 + srow;       // 4 chunks cover 64 B-rows
                gll16(W + (size_t)(col0 + rr) * K + k0 + scol, &Bs[w * 512]);
            }
        }
        __syncthreads();
        bf16x8 af[MI], bf[4];
#pragma unroll
        for (int i = 0; i < MI; ++i)
            af[i] = *(const bf16x8*)&As[(wr + i * 16 + m16) * 32 + quad * 8];
#pragma unroll
        for (int j = 0; j < 4; ++j)
            bf[j] = *(const bf16x8*)&Bs[(wc + j * 16 + m16) * 32 + quad * 8];
#pragma unroll
        for (int i = 0; i < MI; ++i)
#pragma unroll
            for (int j = 0; j < 4; ++j) acc[i][j] = MFMA16(af[i], bf[j], acc[i][j]);
        __syncthreads();
    }
    // epilogue: D[row=quad*4+r][col=m16] per 16x16 tile
#pragma unroll
    for (int i = 0; i < MI; ++i)
#pragma unroll
        for (int j = 0; j < 4; ++j)
#pragma unroll
            for (int r = 0; r < 4; ++r) {
                const int rg = row0 + wr + i * 16 + quad * 4 + r;
                const int cg = col0 + wc + j * 16 + m16;
                if (OUT_BF16)
                    ((u16*)Yv)[(size_t)rg * N + cg] = f2b(acc[i][j][r]);
                else
                    ((float*)Yv)[(size_t)rg * N + cg] = acc[i][j][r];
            }
}

// ---------------------------------------------------------------- v -> vT
__global__ __launch_bounds__(256) void transpose_v(const u16* __restrict__ v,
                                                   u16* __restrict__ vT, int vstride) {
    __shared__ u16 tile[64][72];
    const int t = threadIdx.x;
    const int tt = blockIdx.x, h = blockIdx.y, b = blockIdx.z;
    {
        const int row = t >> 2, c4 = (t & 3) * 16;
        const u16* src = v + (size_t)(b * 1024 + tt * 64 + row) * vstride + h * 64 + c4;
        *(u16x8*)&tile[row][c4] = *(const u16x8*)src;
        *(u16x8*)&tile[row][c4 + 8] = *(const u16x8*)(src + 8);
    }
    __syncthreads();
    const int vd = t >> 2, tk = (t & 3) * 16;
    u16 tmp[16];
#pragma unroll
    for (int j = 0; j < 16; ++j) tmp[j] = tile[tk + j][vd];
    u16* dst = vT + (size_t)((b * 16 + h) * 64 + vd) * 1024 + tt * 64 + tk;
    *(u16x8*)dst = *(u16x8*)tmp;
    *(u16x8*)(dst + 8) = *(u16x8*)(tmp + 8);
}

// ---------------------------------------------------------------- based attention
// Block: 128 q-rows for one (b,h). Heavy tiles first (qt2 = 7 - blockIdx.x).
// S^T = K*Q^T (packed Ss writes), num = Ss*V, den via ones-B MFMA.
// Ss rows are wave-private -> no barrier between phase 1 and phase 2.
__global__ __launch_bounds__(256) void based_attn(const u16* __restrict__ q,
                                                  const u16* __restrict__ k,
                                                  const u16* __restrict__ vT,
                                                  u16* __restrict__ o) {
    __shared__ u16 qs[2][128][32];   // [d-block][q][32]
    __shared__ u16 ks[2][64][32];    // [d-block][key][32]
    __shared__ u16 vs[2][64][32];    // [key-block][vdim][32 keys]
    __shared__ u16 Ss[2][128][32];   // [key-block][q][32 keys]

    const int t = threadIdx.x, w = t >> 6, lane = t & 63;
    const int quad = lane >> 4, m16 = lane & 15;
    const int qt2 = 7 - blockIdx.x;  // heavy blocks dispatch first
    const int h = blockIdx.y, b = blockIdx.z;
    const int Q0 = qt2 * 128;
    const int srow = lane >> 2, s8 = (lane & 3) * 8;
    const int qw0 = Q0 + w * 32;     // first q-row this wave owns

    // stage q tile (16 chunks of 1KB; wave w: 4w..4w+3)
#pragma unroll
    for (int cc = 0; cc < 4; ++cc) {
        const int c = w * 4 + cc;
        const int dblk = c >> 3, rr = (c & 7) * 16 + srow;
        gll16(q + (size_t)(b * 1024 + Q0 + rr) * 3072 + h * 64 + dblk * 32 + s8,
              &qs[dblk][(c & 7) * 16][0]);
    }

    bf16x8 ones;
#pragma unroll
    for (int e = 0; e < 8; ++e) ones[e] = (short)0x3F80;

    f32x4 num[2][4], den[2];
#pragma unroll
    for (int i = 0; i < 2; ++i) {
        den[i] = (f32x4){0.f, 0.f, 0.f, 0.f};
#pragma unroll
        for (int j = 0; j < 4; ++j) num[i][j] = (f32x4){0.f, 0.f, 0.f, 0.f};
    }

    const int ktmax = 2 * qt2 + 1;
    for (int kt = 0; kt <= ktmax; ++kt) {
        // stage k (8 chunks) and vT (8 chunks); wave w: chunks 2w, 2w+1
#pragma unroll
        for (int cc = 0; cc < 2; ++cc) {
            const int c = w * 2 + cc;
            const int blk = c >> 2, rr = (c & 3) * 16 + srow;
            gll16(k + (size_t)(b * 1024 + kt * 64 + rr) * 3072 + h * 64 + blk * 32 + s8,
                  &ks[blk][(c & 3) * 16][0]);
            gll16(vT + (size_t)((b * 16 + h) * 64 + rr) * 1024 + kt * 64 + blk * 32 + s8,
                  &vs[blk][(c & 3) * 16][0]);
        }
        __syncthreads();   // covers qs (first iter) + ks/vs

        // wave-uniform: does this wave see any visible key in this tile?
        const bool active = (kt * 64 <= qw0 + 31);
        if (active) {
            // Phase 1: S^T tiles: D[key][q] = K[key][d] * Q^T[d][q]
            f32x4 sacc[2][4];
#pragma unroll
            for (int iq = 0; iq < 2; ++iq)
#pragma unroll
                for (int jk = 0; jk < 4; ++jk) sacc[iq][jk] = (f32x4){0.f, 0.f, 0.f, 0.f};
#pragma unroll
            for (int kd = 0; kd < 2; ++kd) {
                bf16x8 af[4], qf[2];
#pragma unroll
                for (int jk = 0; jk < 4; ++jk)
                    af[jk] = *(const bf16x8*)&ks[kd][jk * 16 + m16][quad * 8];
#pragma unroll
                for (int iq = 0; iq < 2; ++iq)
                    qf[iq] = *(const bf16x8*)&qs[kd][w * 32 + iq * 16 + m16][quad * 8];
#pragma unroll
                for (int iq = 0; iq < 2; ++iq)
#pragma unroll
                    for (int jk = 0; jk < 4; ++jk)
                        sacc[iq][jk] = MFMA16(af[jk], qf[iq], sacc[iq][jk]);
            }
            // transform: sc = 0.5*(s+1)^2 + 0.5, s = dot/8; mask only on diagonal
            const bool needMask = (kt * 64 + 63 > qw0);
#pragma unroll
            for (int iq = 0; iq < 2; ++iq) {
                const int qglob = qw0 + iq * 16 + m16;
#pragma unroll
                for (int jk = 0; jk < 4; ++jk) {
                    const int key0 = kt * 64 + jk * 16 + quad * 4;
                    float sc[4];
#pragma unroll
                    for (int r = 0; r < 4; ++r) {
                        const float u = fmaf(sacc[iq][jk][r], 0.125f, 1.0f);
                        sc[r] = fmaf(u * 0.5f, u, 0.5f);
                    }
                    if (needMask) {
#pragma unroll
                        for (int r = 0; r < 4; ++r)
                            if (key0 + r > qglob) sc[r] = 0.f;
                    }
                    const int kl = jk * 16 + quad * 4;
                    *(uint2*)&Ss[kl >> 5][w * 32 + iq * 16 + m16][kl & 31] =
                        make_uint2(pkbf(sc[0], sc[1]), pkbf(sc[2], sc[3]));
                }
            }
            // Phase 2 (no barrier needed: Ss rows are wave-private)
#pragma unroll
            for (int kb = 0; kb < 2; ++kb) {
                bf16x8 sf[2], vf[4];
#pragma unroll
                for (int i = 0; i < 2; ++i)
                    sf[i] = *(const bf16x8*)&Ss[kb][w * 32 + i * 16 + m16][quad * 8];
#pragma unroll
                for (int j = 0; j < 4; ++j)
                    vf[j] = *(const bf16x8*)&vs[kb][j * 16 + m16][quad * 8];
#pragma unroll
                for (int i = 0; i < 2; ++i) {
#pragma unroll
                    for (int j = 0; j < 4; ++j) num[i][j] = MFMA16(sf[i], vf[j], num[i][j]);
                    den[i] = MFMA16(sf[i], ones, den[i]);
                }
            }
        }
        __syncthreads();   // before next iter overwrites ks/vs
    }

    // epilogue: o[q][h*64+vdim] = num/den, bf16
#pragma unroll
    for (int i = 0; i < 2; ++i)
#pragma unroll
        for (int r = 0; r < 4; ++r) {
            const float inv = 1.0f / den[i][r];
            const int tok = b * 1024 + Q0 + w * 32 + i * 16 + quad * 4 + r;
#pragma unroll
            for (int j = 0; j < 4; ++j)
                o[(size_t)tok * 1024 + h * 64 + j * 16 + m16] = f2b(num[i][j][r] * inv);
        }
}

// ---------------------------------------------------------------- launch
extern "C" void kernel_launch(void* const* d_in, const int* in_sizes, int n_in,
                              void* d_out, int out_size, void* d_ws, size_t ws_size,
                              hipStream_t stream) {
    const float* x  = (const float*)d_in[0];
    const float* Wq = (const float*)d_in[1];
    const float* Wk = (const float*)d_in[2];
    const float* Wv = (const float*)d_in[3];
    const float* Wo = (const float*)d_in[4];
    float* out = (float*)d_out;

    const size_t MEL = 4096ull * 1024ull;   // 4M
    u16* xb   = (u16*)d_ws;            // 4M elems
    u16* Wqkv = xb + MEL;              // 3M (Wq|Wk|Wv rows concatenated)
    u16* Wob  = Wqkv + 3ull * 1024 * 1024;   // 1M (contiguous after Wqkv)
    u16* qkv  = Wob + 1024ull * 1024;  // 4096 x 3072
    u16* vT   = qkv + 3ull * MEL;      // (b,h,vdim) x 1024 tokens
    u16* o    = vT + MEL;              // 4096 x 1024

    cast_x<<<2048, 256, 0, stream>>>(x, xb);
    cast_w<<<dim3(512, 4), 256, 0, stream>>>(Wq, Wk, Wv, Wo, Wqkv);

    dim3 gq(32, 24);   // 4096/128 x 3072/128
    gemm_bt<128, 1><<<gq, 256, 0, stream>>>(xb, Wqkv, qkv, 4096, 3072, 1024);

    dim3 gt(16, 16, 4);
    transpose_v<<<gt, 256, 0, stream>>>(qkv + 2048, vT, 3072);

    dim3 ga(8, 16, 4);   // 128-row q-tiles (heavy first) x heads x batch
    based_attn<<<ga, 256, 0, stream>>>(qkv, qkv + 1024, vT, o);

    dim3 go(32, 16);   // 128x64 tiles -> 512 blocks, 2/CU
    gemm_bt<64, 0><<<go, 256, 0, stream>>>(o, Wob, (void*)out, 4096, 1024, 1024);
}

// Round 7
// 170.660 us; speedup vs baseline: 9.9653x; 1.0973x over previous
//
#include <hip/hip_runtime.h>

typedef unsigned short u16;
typedef __attribute__((ext_vector_type(8))) short bf16x8;   // MFMA A/B frag (8 bf16)
typedef __attribute__((ext_vector_type(8))) unsigned short u16x8;
typedef __attribute__((ext_vector_type(4))) float f32x4;    // MFMA C/D frag

#define MFMA16(a, b, c) __builtin_amdgcn_mfma_f32_16x16x32_bf16((a), (b), (c), 0, 0, 0)

// async global->LDS, 16B per lane; LDS dest = wave-uniform base + lane*16
__device__ __forceinline__ void gll16(const void* g, void* l) {
    __builtin_amdgcn_global_load_lds(
        (const __attribute__((address_space(1))) unsigned int*)g,
        (__attribute__((address_space(3))) unsigned int*)l, 16, 0, 0);
}

__device__ __forceinline__ u16 f2b(float f) {   // f32 -> bf16 RNE (scalar)
    unsigned int u = __float_as_uint(f);
    u += 0x7fffu + ((u >> 16) & 1u);
    return (u16)(u >> 16);
}

__device__ __forceinline__ unsigned int pkbf(float a, float b) {  // packed bf16x2
    return (unsigned int)f2b(a) | ((unsigned int)f2b(b) << 16);
}

// ---------------------------------------------------------------- one cast kernel
// blocks 0..2047: x (4M f32). blocks 2048..4095: the four 1M-element weights.
__global__ __launch_bounds__(256) void cast_all(const float* __restrict__ x,
                                                const float* __restrict__ w0,
                                                const float* __restrict__ w1,
                                                const float* __restrict__ w2,
                                                const float* __restrict__ w3,
                                                u16* __restrict__ xb,
                                                u16* __restrict__ wb) {
    const int bid = blockIdx.x;
    const float* s; u16* d; int off;
    if (bid < 2048) { s = x; d = xb; off = bid; }
    else {
        const int wi = (bid - 2048) >> 9;
        s = (wi == 0) ? w0 : (wi == 1) ? w1 : (wi == 2) ? w2 : w3;
        d = wb + (size_t)wi * 1048576;
        off = (bid - 2048) & 511;
    }
    const int i = (off * 256 + threadIdx.x) * 8;
    float4 a = *(const float4*)(s + i);
    float4 b = *(const float4*)(s + i + 4);
    *(uint4*)(d + i) = make_uint4(pkbf(a.x, a.y), pkbf(a.z, a.w),
                                  pkbf(b.x, b.y), pkbf(b.z, b.w));
}

// ---------------------------------------------------------------- GEMM (m97 style)
// Y = A[M,K] @ W[rows,K]^T, bf16 in, fp32 acc, 128xBN tile, BK=32, 4 waves.
// MODE 0: f32 out, stride ldY (final o-GEMM, BN=64 for occupancy).
// MODE 1: fused QKV epilogue — cols <2048 -> bf16 qk (stride 2048);
//         cols >=2048 (the V projection) -> transposed into vT[b*1024+hv][token].
template <int BN, int MODE>
__global__ __launch_bounds__(256) void gemm_bt(const u16* __restrict__ A,
                                               const u16* __restrict__ W,
                                               void* __restrict__ Yv,
                                               u16* __restrict__ vT,
                                               int K, int ldY) {
    __shared__ u16 As[128 * 32];
    __shared__ u16 Bs[BN * 32];
    constexpr int MI = (BN == 128) ? 4 : 2;
    const int t = threadIdx.x, w = t >> 6, lane = t & 63;
    const int quad = lane >> 4, m16 = lane & 15;
    const int wr = (BN == 128) ? ((w >> 1) * 64) : (w * 32);
    const int wc = (BN == 128) ? ((w & 1) * 64) : 0;
    const int row0 = blockIdx.x * 128, col0 = blockIdx.y * BN;
    const int srow = lane >> 2;           // staging: row within 16-row chunk
    const int scol = (lane & 3) * 8;      // staging: 8-elem col offset

    f32x4 acc[MI][4];
#pragma unroll
    for (int i = 0; i < MI; ++i)
#pragma unroll
        for (int j = 0; j < 4; ++j) acc[i][j] = (f32x4){0.f, 0.f, 0.f, 0.f};

    for (int k0 = 0; k0 < K; k0 += 32) {
        if constexpr (BN == 128) {
#pragma unroll
            for (int cc = 0; cc < 2; ++cc) {
                const int c = w * 2 + cc;           // chunk 0..7 (16 rows x 64B)
                const int rr = c * 16 + srow;
                gll16(A + (size_t)(row0 + rr) * K + k0 + scol, &As[c * 512]);
                gll16(W + (size_t)(col0 + rr) * K + k0 + scol, &Bs[c * 512]);
            }
        } else {
#pragma unroll
            for (int cc = 0; cc < 2; ++cc) {
                const int c = w * 2 + cc;
                const int rr = c * 16 + srow;
                gll16(A + (size_t)(row0 + rr) * K + k0 + scol, &As[c * 512]);
            }
            {
                const int rr = w * 16 + srow;       // 4 chunks cover 64 B-rows
                gll16(W + (size_t)(col0 + rr) * K + k0 + scol, &Bs[w * 512]);
            }
        }
        __syncthreads();
        bf16x8 af[MI], bf[4];
#pragma unroll
        for (int i = 0; i < MI; ++i)
            af[i] = *(const bf16x8*)&As[(wr + i * 16 + m16) * 32 + quad * 8];
#pragma unroll
        for (int j = 0; j < 4; ++j)
            bf[j] = *(const bf16x8*)&Bs[(wc + j * 16 + m16) * 32 + quad * 8];
#pragma unroll
        for (int i = 0; i < MI; ++i)
#pragma unroll
            for (int j = 0; j < 4; ++j) acc[i][j] = MFMA16(af[i], bf[j], acc[i][j]);
        __syncthreads();
    }
    // epilogue: D[row=quad*4+r][col=m16] per 16x16 tile
    if constexpr (MODE == 0) {
#pragma unroll
        for (int i = 0; i < MI; ++i)
#pragma unroll
            for (int j = 0; j < 4; ++j)
#pragma unroll
                for (int r = 0; r < 4; ++r)
                    ((float*)Yv)[(size_t)(row0 + wr + i * 16 + quad * 4 + r) * ldY +
                                 col0 + wc + j * 16 + m16] = acc[i][j][r];
    } else {
        if (col0 < 2048) {              // Q/K projection -> bf16, stride 2048
            u16* qk = (u16*)Yv;
#pragma unroll
            for (int i = 0; i < MI; ++i)
#pragma unroll
                for (int j = 0; j < 4; ++j)
#pragma unroll
                    for (int r = 0; r < 4; ++r)
                        qk[(size_t)(row0 + wr + i * 16 + quad * 4 + r) * 2048 +
                           col0 + wc + j * 16 + m16] = f2b(acc[i][j][r]);
        } else {                        // V projection -> transposed vT
#pragma unroll
            for (int i = 0; i < MI; ++i) {
                const int rbase = row0 + wr + i * 16;
                const int bb = rbase >> 10;
                const int tok0 = (rbase & 1023) + quad * 4;
#pragma unroll
                for (int j = 0; j < 4; ++j) {
                    const int vTrow = bb * 1024 + (col0 + wc + j * 16 + m16 - 2048);
                    *(uint2*)(vT + (size_t)vTrow * 1024 + tok0) =
                        make_uint2(pkbf(acc[i][j][0], acc[i][j][1]),
                                   pkbf(acc[i][j][2], acc[i][j][3]));
                }
            }
        }
    }
}

// ---------------------------------------------------------------- based attention
// Triangular pairing: block p handles q-tiles tA=p and tB=15-p (64 rows each)
// => every block does exactly 17 tile-units (perfect balance), and tA's key
// range [0..p] is a subset of tB's [0..15-p], so one k/v staging serves both.
// k/v double-buffered; ONE __syncthreads per kt-iter (loads for kt+1 issued
// right after the barrier hide their latency behind kt's compute).
// D-layout convention (verified round 2): MFMA16(Xfrag, Yfrag, acc) gives
// acc row quad*4+reg = X's m-dim, col m16 = Y's m-dim.
__global__ __launch_bounds__(256) void based_attn(const u16* __restrict__ qkm,
                                                  const u16* __restrict__ vT,
                                                  u16* __restrict__ o) {
    __shared__ u16 qsA[2][64][32];      // [dblk][qrow][32]
    __shared__ u16 qsB[2][64][32];
    __shared__ u16 ks[2][2][64][32];    // [buf][dblk][key][32]
    __shared__ u16 vs[2][2][64][32];    // [buf][kb][vdim][32 keys]
    __shared__ u16 Ss[2][64][32];       // [kb][qrow][32 keys]  (wave-private rows)

    const int t = threadIdx.x, w = t >> 6, lane = t & 63;
    const int quad = lane >> 4, m16 = lane & 15;
    const int p = blockIdx.x, h = blockIdx.y, b = blockIdx.z;
    const int tA = p, tB = 15 - p;
    const int srow = lane >> 2, s8 = (lane & 3) * 8;

    const size_t qbase = (size_t)b * 1024 * 2048 + h * 64;
    const size_t kbase = qbase + 1024;
    const size_t vbase = ((size_t)b * 1024 + h * 64) * 1024;

    // prologue: q tiles A and B (8 chunks each); wave w takes chunks w*4+cc
#pragma unroll
    for (int cc = 0; cc < 4; ++cc) {
        const int c = w * 4 + cc;
        const int tile = c >> 3, dblk = (c >> 2) & 1, rc = c & 3;
        const int Q0 = (tile ? tB : tA) * 64;
        gll16(qkm + qbase + (size_t)(Q0 + rc * 16 + srow) * 2048 + dblk * 32 + s8,
              tile ? &qsB[dblk][rc * 16][0] : &qsA[dblk][rc * 16][0]);
    }
    // prologue: k/v tile kt=0 into buf 0; wave w takes chunks 2w,2w+1
#pragma unroll
    for (int cc = 0; cc < 2; ++cc) {
        const int c = w * 2 + cc;
        const int blk = c >> 2, rc = c & 3;
        gll16(qkm + kbase + (size_t)(rc * 16 + srow) * 2048 + blk * 32 + s8,
              &ks[0][blk][rc * 16][0]);
        gll16(vT + vbase + (size_t)(rc * 16 + srow) * 1024 + blk * 32 + s8,
              &vs[0][blk][rc * 16][0]);
    }

    bf16x8 ones;
#pragma unroll
    for (int e = 0; e < 8; ++e) ones[e] = (short)0x3F80;

    f32x4 numA[4], numB[4], denA, denB;
    denA = denB = (f32x4){0.f, 0.f, 0.f, 0.f};
#pragma unroll
    for (int j = 0; j < 4; ++j) numA[j] = numB[j] = (f32x4){0.f, 0.f, 0.f, 0.f};

    // per-tile compute: phase1 S^T = K·Q^T, transform (+diag mask), phase2 S·V.
#define TILE_COMPUTE(QS, NUM, DEN, DIAG)                                        \
    {                                                                           \
        f32x4 sacc[4];                                                          \
        _Pragma("unroll")                                                       \
        for (int jk = 0; jk < 4; ++jk) sacc[jk] = (f32x4){0.f, 0.f, 0.f, 0.f};  \
        _Pragma("unroll")                                                       \
        for (int kd = 0; kd < 2; ++kd) {                                        \
            bf16x8 qf = *(const bf16x8*)&QS[kd][w * 16 + m16][quad * 8];        \
            _Pragma("unroll")                                                   \
            for (int jk = 0; jk < 4; ++jk) {                                    \
                bf16x8 af = *(const bf16x8*)&ks[buf][kd][jk * 16 + m16][quad * 8]; \
                sacc[jk] = MFMA16(af, qf, sacc[jk]);                            \
            }                                                                   \
        }                                                                       \
        _Pragma("unroll")                                                       \
        for (int jk = 0; jk < 4; ++jk) {                                        \
            float sc[4];                                                        \
            _Pragma("unroll")                                                   \
            for (int r = 0; r < 4; ++r) {                                       \
                const float u = fmaf(sacc[jk][r], 0.125f, 1.0f);                \
                sc[r] = fmaf(u * 0.5f, u, 0.5f);                                \
            }                                                                   \
            if (DIAG) {                                                         \
                const int key0 = jk * 16 + quad * 4, qr = w * 16 + m16;         \
                _Pragma("unroll")                                               \
                for (int r = 0; r < 4; ++r)                                     \
                    if (key0 + r > qr) sc[r] = 0.f;                             \
            }                                                                   \
            const int kl = jk * 16 + quad * 4;                                  \
            *(uint2*)&Ss[kl >> 5][w * 16 + m16][kl & 31] =                      \
                make_uint2(pkbf(sc[0], sc[1]), pkbf(sc[2], sc[3]));             \
        }                                                                       \
        _Pragma("unroll")                                                       \
        for (int kb = 0; kb < 2; ++kb) {                                        \
            bf16x8 sf = *(const bf16x8*)&Ss[kb][w * 16 + m16][quad * 8];        \
            _Pragma("unroll")                                                   \
            for (int j = 0; j < 4; ++j) {                                       \
                bf16x8 vf = *(const bf16x8*)&vs[buf][kb][j * 16 + m16][quad * 8]; \
                NUM[j] = MFMA16(sf, vf, NUM[j]);                                \
            }                                                                   \
            DEN = MFMA16(sf, ones, DEN);                                        \
        }                                                                       \
    }

    for (int kt = 0; kt <= tB; ++kt) {
        const int buf = kt & 1;
        __syncthreads();                 // loads for kt landed; buf^1 free to refill
        if (kt < tB) {
            const int nb = buf ^ 1, kn = kt + 1;
#pragma unroll
            for (int cc = 0; cc < 2; ++cc) {
                const int c = w * 2 + cc;
                const int blk = c >> 2, rc = c & 3;
                gll16(qkm + kbase + (size_t)(kn * 64 + rc * 16 + srow) * 2048 + blk * 32 + s8,
                      &ks[nb][blk][rc * 16][0]);
                gll16(vT + vbase + (size_t)(rc * 16 + srow) * 1024 + kn * 64 + blk * 32 + s8,
                      &vs[nb][blk][rc * 16][0]);
            }
        }
        TILE_COMPUTE(qsB, numB, denB, (kt == tB));
        if (kt <= tA) TILE_COMPUTE(qsA, numA, denA, (kt == tA));
    }
#undef TILE_COMPUTE

    // epilogue: o[token][h*64+vdim] = num/den (bf16)
#pragma unroll
    for (int r = 0; r < 4; ++r) {
        const float invA = 1.0f / denA[r], invB = 1.0f / denB[r];
        const int rowoff = w * 16 + quad * 4 + r;
        const size_t tokA = (size_t)(b * 1024 + tA * 64 + rowoff);
        const size_t tokB = (size_t)(b * 1024 + tB * 64 + rowoff);
#pragma unroll
        for (int j = 0; j < 4; ++j) {
            o[tokA * 1024 + h * 64 + j * 16 + m16] = f2b(numA[j][r] * invA);
            o[tokB * 1024 + h * 64 + j * 16 + m16] = f2b(numB[j][r] * invB);
        }
    }
}

// ---------------------------------------------------------------- launch
extern "C" void kernel_launch(void* const* d_in, const int* in_sizes, int n_in,
                              void* d_out, int out_size, void* d_ws, size_t ws_size,
                              hipStream_t stream) {
    const float* x  = (const float*)d_in[0];
    const float* Wq = (const float*)d_in[1];
    const float* Wk = (const float*)d_in[2];
    const float* Wv = (const float*)d_in[3];
    const float* Wo = (const float*)d_in[4];
    float* out = (float*)d_out;

    const size_t MEL = 4096ull * 1024ull;        // 4M elements
    u16* xb   = (u16*)d_ws;                      // 4096 x 1024
    u16* Wqkv = xb + MEL;                        // 3072 x 1024 (Wq|Wk|Wv rows)
    u16* Wob  = Wqkv + 3ull * 1024 * 1024;       // 1024 x 1024 (contiguous after)
    u16* qk   = Wob + 1024ull * 1024;            // 4096 x 2048 (q|k)
    u16* vT   = qk + 2ull * MEL;                 // [b*1024+h*64+vd][1024 tokens]
    u16* o    = vT + MEL;                        // 4096 x 1024

    cast_all<<<4096, 256, 0, stream>>>(x, Wq, Wk, Wv, Wo, xb, Wqkv);

    dim3 gq(32, 24);   // 4096/128 x 3072/128; y>=16 blocks write vT directly
    gemm_bt<128, 1><<<gq, 256, 0, stream>>>(xb, Wqkv, qk, vT, 1024, 2048);

    dim3 ga(8, 16, 4); // pair index x heads x batch — uniform work per block
    based_attn<<<ga, 256, 0, stream>>>(qk, vT, o);

    dim3 go(32, 16);   // 128x64 tiles -> 512 blocks, 2/CU
    gemm_bt<64, 0><<<go, 256, 0, stream>>>(o, Wob, (void*)out, nullptr, 1024, 1024);
}

// Round 8
// 165.314 us; speedup vs baseline: 10.2876x; 1.0323x over previous
//
#include <hip/hip_runtime.h>

typedef unsigned short u16;
typedef __attribute__((ext_vector_type(8))) short bf16x8;   // MFMA A/B frag (8 bf16)
typedef __attribute__((ext_vector_type(8))) unsigned short u16x8;
typedef __attribute__((ext_vector_type(4))) float f32x4;    // MFMA C/D frag

#define MFMA16(a, b, c) __builtin_amdgcn_mfma_f32_16x16x32_bf16((a), (b), (c), 0, 0, 0)

// async global->LDS, 16B per lane; LDS dest = wave-uniform base + lane*16
__device__ __forceinline__ void gll16(const void* g, void* l) {
    __builtin_amdgcn_global_load_lds(
        (const __attribute__((address_space(1))) unsigned int*)g,
        (__attribute__((address_space(3))) unsigned int*)l, 16, 0, 0);
}

__device__ __forceinline__ u16 f2b(float f) {   // f32 -> bf16 RNE (scalar)
    unsigned int u = __float_as_uint(f);
    u += 0x7fffu + ((u >> 16) & 1u);
    return (u16)(u >> 16);
}

__device__ __forceinline__ unsigned int pkbf(float a, float b) {  // packed bf16x2
    return (unsigned int)f2b(a) | ((unsigned int)f2b(b) << 16);
}

// ---------------------------------------------------------------- one cast kernel
// blocks 0..2047: x (4M f32). blocks 2048..4095: the four 1M-element weights.
__global__ __launch_bounds__(256) void cast_all(const float* __restrict__ x,
                                                const float* __restrict__ w0,
                                                const float* __restrict__ w1,
                                                const float* __restrict__ w2,
                                                const float* __restrict__ w3,
                                                u16* __restrict__ xb,
                                                u16* __restrict__ wb) {
    const int bid = blockIdx.x;
    const float* s; u16* d; int off;
    if (bid < 2048) { s = x; d = xb; off = bid; }
    else {
        const int wi = (bid - 2048) >> 9;
        s = (wi == 0) ? w0 : (wi == 1) ? w1 : (wi == 2) ? w2 : w3;
        d = wb + (size_t)wi * 1048576;
        off = (bid - 2048) & 511;
    }
    const int i = (off * 256 + threadIdx.x) * 8;
    float4 a = *(const float4*)(s + i);
    float4 b = *(const float4*)(s + i + 4);
    *(uint4*)(d + i) = make_uint4(pkbf(a.x, a.y), pkbf(a.z, a.w),
                                  pkbf(b.x, b.y), pkbf(b.z, b.w));
}

// ---------------------------------------------------------------- GEMM, dbuf K-loop
// Y = A[M,K] @ W[rows,K]^T, bf16 in, fp32 acc, BMxBN tile, BK=32, 4 waves (2x2),
// LDS double-buffered: ONE barrier per iter, prefetch for k+1 issued right after
// the barrier so its latency is hidden behind this iter's compute (attn structure).
// MODE 0: f32 out, stride ldY. MODE 1 (BM=BN=128): fused QKV epilogue — cols<2048
// -> bf16 qk (stride 2048); cols>=2048 (V proj) -> transposed into vT.
template <int BM, int BN, int MODE>
__global__ __launch_bounds__(256) void gemm_bt(const u16* __restrict__ A,
                                               const u16* __restrict__ W,
                                               void* __restrict__ Yv,
                                               u16* __restrict__ vT,
                                               int K, int ldY) {
    constexpr int MI = BM / 32, NJ = BN / 32;      // frags per wave
    constexpr int ACH = BM / 16;                   // A staging chunks (1KB each)
    constexpr int NPW = (BM + BN) / 64;            // chunks per wave
    __shared__ u16 As[2][BM * 32];
    __shared__ u16 Bs[2][BN * 32];
    const int t = threadIdx.x, w = t >> 6, lane = t & 63;
    const int quad = lane >> 4, m16 = lane & 15;
    const int wr = (w >> 1) * (BM / 2), wc = (w & 1) * (BN / 2);
    const int row0 = blockIdx.x * BM, col0 = blockIdx.y * BN;
    const int srow = lane >> 2, scol = (lane & 3) * 8;

    auto stage = [&](int buf, int k0) {
#pragma unroll
        for (int cc = 0; cc < NPW; ++cc) {
            const int c = w * NPW + cc;
            if (c < ACH)
                gll16(A + (size_t)(row0 + c * 16 + srow) * K + k0 + scol,
                      &As[buf][c * 512]);
            else
                gll16(W + (size_t)(col0 + (c - ACH) * 16 + srow) * K + k0 + scol,
                      &Bs[buf][(c - ACH) * 512]);
        }
    };

    f32x4 acc[MI][NJ];
#pragma unroll
    for (int i = 0; i < MI; ++i)
#pragma unroll
        for (int j = 0; j < NJ; ++j) acc[i][j] = (f32x4){0.f, 0.f, 0.f, 0.f};

    stage(0, 0);
    for (int k0 = 0; k0 < K; k0 += 32) {
        const int buf = (k0 >> 5) & 1;
        __syncthreads();                       // tile k0 landed; buf^1 free
        if (k0 + 32 < K) stage(buf ^ 1, k0 + 32);   // hidden behind compute
        bf16x8 af[MI], bf[NJ];
#pragma unroll
        for (int i = 0; i < MI; ++i)
            af[i] = *(const bf16x8*)&As[buf][(wr + i * 16 + m16) * 32 + quad * 8];
#pragma unroll
        for (int j = 0; j < NJ; ++j)
            bf[j] = *(const bf16x8*)&Bs[buf][(wc + j * 16 + m16) * 32 + quad * 8];
#pragma unroll
        for (int i = 0; i < MI; ++i)
#pragma unroll
            for (int j = 0; j < NJ; ++j) acc[i][j] = MFMA16(af[i], bf[j], acc[i][j]);
    }
    // epilogue: D[row=quad*4+r][col=m16] per 16x16 tile
    if constexpr (MODE == 0) {
#pragma unroll
        for (int i = 0; i < MI; ++i)
#pragma unroll
            for (int j = 0; j < NJ; ++j)
#pragma unroll
                for (int r = 0; r < 4; ++r)
                    ((float*)Yv)[(size_t)(row0 + wr + i * 16 + quad * 4 + r) * ldY +
                                 col0 + wc + j * 16 + m16] = acc[i][j][r];
    } else {
        if (col0 < 2048) {              // Q/K projection -> bf16, stride 2048
            u16* qk = (u16*)Yv;
#pragma unroll
            for (int i = 0; i < MI; ++i)
#pragma unroll
                for (int j = 0; j < NJ; ++j)
#pragma unroll
                    for (int r = 0; r < 4; ++r)
                        qk[(size_t)(row0 + wr + i * 16 + quad * 4 + r) * 2048 +
                           col0 + wc + j * 16 + m16] = f2b(acc[i][j][r]);
        } else {                        // V projection -> transposed vT
#pragma unroll
            for (int i = 0; i < MI; ++i) {
                const int rbase = row0 + wr + i * 16;
                const int bb = rbase >> 10;
                const int tok0 = (rbase & 1023) + quad * 4;
#pragma unroll
                for (int j = 0; j < NJ; ++j) {
                    const int vTrow = bb * 1024 + (col0 + wc + j * 16 + m16 - 2048);
                    *(uint2*)(vT + (size_t)vTrow * 1024 + tok0) =
                        make_uint2(pkbf(acc[i][j][0], acc[i][j][1]),
                                   pkbf(acc[i][j][2], acc[i][j][3]));
                }
            }
        }
    }
}

// ---------------------------------------------------------------- based attention
// Triangular pairing: block p handles q-tiles tA=p and tB=15-p (64 rows each)
// => every block does exactly 17 tile-units (perfect balance), and tA's key
// range [0..p] is a subset of tB's [0..15-p], so one k/v staging serves both.
// k/v double-buffered; ONE __syncthreads per kt-iter (loads for kt+1 issued
// right after the barrier hide their latency behind kt's compute).
__global__ __launch_bounds__(256) void based_attn(const u16* __restrict__ qkm,
                                                  const u16* __restrict__ vT,
                                                  u16* __restrict__ o) {
    __shared__ u16 qsA[2][64][32];      // [dblk][qrow][32]
    __shared__ u16 qsB[2][64][32];
    __shared__ u16 ks[2][2][64][32];    // [buf][dblk][key][32]
    __shared__ u16 vs[2][2][64][32];    // [buf][kb][vdim][32 keys]
    __shared__ u16 Ss[2][64][32];       // [kb][qrow][32 keys]  (wave-private rows)

    const int t = threadIdx.x, w = t >> 6, lane = t & 63;
    const int quad = lane >> 4, m16 = lane & 15;
    const int p = blockIdx.x, h = blockIdx.y, b = blockIdx.z;
    const int tA = p, tB = 15 - p;
    const int srow = lane >> 2, s8 = (lane & 3) * 8;

    const size_t qbase = (size_t)b * 1024 * 2048 + h * 64;
    const size_t kbase = qbase + 1024;
    const size_t vbase = ((size_t)b * 1024 + h * 64) * 1024;

    // prologue: q tiles A and B (8 chunks each); wave w takes chunks w*4+cc
#pragma unroll
    for (int cc = 0; cc < 4; ++cc) {
        const int c = w * 4 + cc;
        const int tile = c >> 3, dblk = (c >> 2) & 1, rc = c & 3;
        const int Q0 = (tile ? tB : tA) * 64;
        gll16(qkm + qbase + (size_t)(Q0 + rc * 16 + srow) * 2048 + dblk * 32 + s8,
              tile ? &qsB[dblk][rc * 16][0] : &qsA[dblk][rc * 16][0]);
    }
    // prologue: k/v tile kt=0 into buf 0; wave w takes chunks 2w,2w+1
#pragma unroll
    for (int cc = 0; cc < 2; ++cc) {
        const int c = w * 2 + cc;
        const int blk = c >> 2, rc = c & 3;
        gll16(qkm + kbase + (size_t)(rc * 16 + srow) * 2048 + blk * 32 + s8,
              &ks[0][blk][rc * 16][0]);
        gll16(vT + vbase + (size_t)(rc * 16 + srow) * 1024 + blk * 32 + s8,
              &vs[0][blk][rc * 16][0]);
    }

    bf16x8 ones;
#pragma unroll
    for (int e = 0; e < 8; ++e) ones[e] = (short)0x3F80;

    f32x4 numA[4], numB[4], denA, denB;
    denA = denB = (f32x4){0.f, 0.f, 0.f, 0.f};
#pragma unroll
    for (int j = 0; j < 4; ++j) numA[j] = numB[j] = (f32x4){0.f, 0.f, 0.f, 0.f};

    // per-tile compute: phase1 S^T = K·Q^T, transform (+diag mask), phase2 S·V.
#define TILE_COMPUTE(QS, NUM, DEN, DIAG)                                        \
    {                                                                           \
        f32x4 sacc[4];                                                          \
        _Pragma("unroll")                                                       \
        for (int jk = 0; jk < 4; ++jk) sacc[jk] = (f32x4){0.f, 0.f, 0.f, 0.f};  \
        _Pragma("unroll")                                                       \
        for (int kd = 0; kd < 2; ++kd) {                                        \
            bf16x8 qf = *(const bf16x8*)&QS[kd][w * 16 + m16][quad * 8];        \
            _Pragma("unroll")                                                   \
            for (int jk = 0; jk < 4; ++jk) {                                    \
                bf16x8 af = *(const bf16x8*)&ks[buf][kd][jk * 16 + m16][quad * 8]; \
                sacc[jk] = MFMA16(af, qf, sacc[jk]);                            \
            }                                                                   \
        }                                                                       \
        _Pragma("unroll")                                                       \
        for (int jk = 0; jk < 4; ++jk) {                                        \
            float sc[4];                                                        \
            _Pragma("unroll")                                                   \
            for (int r = 0; r < 4; ++r) {                                       \
                const float u = fmaf(sacc[jk][r], 0.125f, 1.0f);                \
                sc[r] = fmaf(u * 0.5f, u, 0.5f);                                \
            }                                                                   \
            if (DIAG) {                                                         \
                const int key0 = jk * 16 + quad * 4, qr = w * 16 + m16;         \
                _Pragma("unroll")                                               \
                for (int r = 0; r < 4; ++r)                                     \
                    if (key0 + r > qr) sc[r] = 0.f;                             \
            }                                                                   \
            const int kl = jk * 16 + quad * 4;                                  \
            *(uint2*)&Ss[kl >> 5][w * 16 + m16][kl & 31] =                      \
                make_uint2(pkbf(sc[0], sc[1]), pkbf(sc[2], sc[3]));             \
        }                                                                       \
        _Pragma("unroll")                                                       \
        for (int kb = 0; kb < 2; ++kb) {                                        \
            bf16x8 sf = *(const bf16x8*)&Ss[kb][w * 16 + m16][quad * 8];        \
            _Pragma("unroll")                                                   \
            for (int j = 0; j < 4; ++j) {                                       \
                bf16x8 vf = *(const bf16x8*)&vs[buf][kb][j * 16 + m16][quad * 8]; \
                NUM[j] = MFMA16(sf, vf, NUM[j]);                                \
            }                                                                   \
            DEN = MFMA16(sf, ones, DEN);                                        \
        }                                                                       \
    }

    for (int kt = 0; kt <= tB; ++kt) {
        const int buf = kt & 1;
        __syncthreads();                 // loads for kt landed; buf^1 free to refill
        if (kt < tB) {
            const int nb = buf ^ 1, kn = kt + 1;
#pragma unroll
            for (int cc = 0; cc < 2; ++cc) {
                const int c = w * 2 + cc;
                const int blk = c >> 2, rc = c & 3;
                gll16(qkm + kbase + (size_t)(kn * 64 + rc * 16 + srow) * 2048 + blk * 32 + s8,
                      &ks[nb][blk][rc * 16][0]);
                gll16(vT + vbase + (size_t)(rc * 16 + srow) * 1024 + kn * 64 + blk * 32 + s8,
                      &vs[nb][blk][rc * 16][0]);
            }
        }
        TILE_COMPUTE(qsB, numB, denB, (kt == tB));
        if (kt <= tA) TILE_COMPUTE(qsA, numA, denA, (kt == tA));
    }
#undef TILE_COMPUTE

    // epilogue: o[token][h*64+vdim] = num/den (bf16)
#pragma unroll
    for (int r = 0; r < 4; ++r) {
        const float invA = 1.0f / denA[r], invB = 1.0f / denB[r];
        const int rowoff = w * 16 + quad * 4 + r;
        const size_t tokA = (size_t)(b * 1024 + tA * 64 + rowoff);
        const size_t tokB = (size_t)(b * 1024 + tB * 64 + rowoff);
#pragma unroll
        for (int j = 0; j < 4; ++j) {
            o[tokA * 1024 + h * 64 + j * 16 + m16] = f2b(numA[j][r] * invA);
            o[tokB * 1024 + h * 64 + j * 16 + m16] = f2b(numB[j][r] * invB);
        }
    }
}

// ---------------------------------------------------------------- launch
extern "C" void kernel_launch(void* const* d_in, const int* in_sizes, int n_in,
                              void* d_out, int out_size, void* d_ws, size_t ws_size,
                              hipStream_t stream) {
    const float* x  = (const float*)d_in[0];
    const float* Wq = (const float*)d_in[1];
    const float* Wk = (const float*)d_in[2];
    const float* Wv = (const float*)d_in[3];
    const float* Wo = (const float*)d_in[4];
    float* out = (float*)d_out;

    const size_t MEL = 4096ull * 1024ull;        // 4M elements
    u16* xb   = (u16*)d_ws;                      // 4096 x 1024
    u16* Wqkv = xb + MEL;                        // 3072 x 1024 (Wq|Wk|Wv rows)
    u16* Wob  = Wqkv + 3ull * 1024 * 1024;       // 1024 x 1024 (contiguous after)
    u16* qk   = Wob + 1024ull * 1024;            // 4096 x 2048 (q|k)
    u16* vT   = qk + 2ull * MEL;                 // [b*1024+h*64+vd][1024 tokens]
    u16* o    = vT + MEL;                        // 4096 x 1024

    cast_all<<<4096, 256, 0, stream>>>(x, Wq, Wk, Wv, Wo, xb, Wqkv);

    dim3 gq(32, 24);   // 4096/128 x 3072/128; y>=16 blocks write vT directly
    gemm_bt<128, 128, 1><<<gq, 256, 0, stream>>>(xb, Wqkv, qk, vT, 1024, 2048);

    dim3 ga(8, 16, 4); // pair index x heads x batch — uniform work per block
    based_attn<<<ga, 256, 0, stream>>>(qk, vT, o);

    dim3 go(64, 16);   // 64x64 tiles -> 1024 blocks, 4/CU, dbuf 16KB LDS
    gemm_bt<64, 64, 0><<<go, 256, 0, stream>>>(o, Wob, (void*)out, nullptr, 1024, 1024);
}